// Round 6
// baseline (185.262 us; speedup 1.0000x reference)
//
#include <hip/hip_runtime.h>
#include <hip/hip_bf16.h>

typedef __attribute__((ext_vector_type(8))) short bf16x8;
typedef __attribute__((ext_vector_type(4))) float f32x4;
typedef __attribute__((ext_vector_type(4))) unsigned short ushort4v;
typedef __attribute__((ext_vector_type(2))) unsigned uint2v;

__device__ __forceinline__ unsigned short f2bf(float f) {
  union { float f; unsigned u; } v; v.f = f;
  unsigned r = v.u + 0x7FFFu + ((v.u >> 16) & 1u);
  return (unsigned short)(r >> 16);
}

__device__ __forceinline__ unsigned pack_bf2(float lo, float hi) {
  __hip_bfloat162 h = __float22bfloat162_rn(make_float2(lo, hi));
  union { __hip_bfloat162 h; unsigned u; } cv; cv.h = h; return cv.u;
}

__device__ __forceinline__ void gll16(const void* g, void* l) {
  __builtin_amdgcn_global_load_lds((const __attribute__((address_space(1))) void*)g,
                                   (__attribute__((address_space(3))) void*)l, 16, 0, 0);
}

#define MFMA16(a, b, c) __builtin_amdgcn_mfma_f32_16x16x32_bf16((a), (b), (c), 0, 0, 0)

// ---------------------------------------------------------------- convert
__global__ void cvt_f32_bf16(const float* __restrict__ s, unsigned short* __restrict__ d, int n) {
  int i = (blockIdx.x * blockDim.x + threadIdx.x) * 4;
  if (i >= n) return;
  float4 f = *(const float4*)(s + i);
  ushort4v r;
  r[0] = f2bf(f.x); r[1] = f2bf(f.y); r[2] = f2bf(f.z); r[3] = f2bf(f.w);
  *(ushort4v*)(d + i) = r;
}

// ---------------------------------------------------------------- GEMM NT, fine-phase schedule
// BM = MIF*32 (256 or 128), BN = 256, BK = 32. 8 waves (2M x 4N), per-wave (MIF*16) x 64.
// A,B each 3-deep ring buffers: A bufs j*ABUF, B bufs BBASE + j*8192 (elems).
// Per K-tile: 2 phases of {4-8 ds_read_b128 + 16(or 8) MFMA}; stage t+2 during t;
// counted vmcnt drain (t+1 complete) at end of tile t.
template<int EPI, int MIF>
__global__ __launch_bounds__(512, 1)
void gemm4p(const unsigned short* __restrict__ A,
            const unsigned short* __restrict__ B,
            unsigned short* __restrict__ obf,
            float* __restrict__ of32,
            int M, int N, int K) {
  extern __shared__ unsigned short lds[];
  constexpr int BM = MIF * 32;
  constexpr int ABUF = BM * 32;           // elems per A buffer (BK=32)
  constexpr int BBASE = 3 * ABUF;
  const int tid = threadIdx.x, wid = tid >> 6, lane = tid & 63;
  const int c = lane & 15, g = lane >> 4;
  const int wm = wid >> 2, wn = wid & 3;
  const int nbn = N >> 8;
  const int nwg = gridDim.x;
  int wg = (blockIdx.x & 7) * (nwg >> 3) + (blockIdx.x >> 3);  // XCD swizzle (nwg%8==0)
  const int m0 = (wg / nbn) * BM, n0 = (wg % nbn) * 256;
  const int NT = K >> 5;
  const size_t rb = (size_t)K * 2;        // global row bytes
  const int swz = (c & 3) << 4;           // ds_read XOR key (16B slots within 64B row)

  // pre-swizzled global source: lane l -> LDS (row16 = l>>2, slot = l&3);
  // global slot' = (l&3) ^ (row16 & 3)
  const int r16 = lane >> 2;
  const int sl = (lane & 3) ^ (r16 & 3);
  const char* Ag = (const char*)A + (size_t)(m0 + r16) * rb + sl * 16;
  const char* Bg = (const char*)B + (size_t)(n0 + r16) * rb + sl * 16;

  auto stageA = [&](int t, int buf) {     // BM/16 chunks of 16 rows x 64B
#pragma unroll
    for (int j = 0; j < MIF / 4; ++j) {
      int ch = wid * (MIF / 4) + j;
      gll16(Ag + (size_t)(ch * 16) * rb + t * 64, lds + buf * ABUF + ch * 512);
    }
  };
  auto stageB = [&](int t, int buf) {     // 16 chunks
#pragma unroll
    for (int j = 0; j < 2; ++j) {
      int ch = wid * 2 + j;
      gll16(Bg + (size_t)(ch * 16) * rb + t * 64, lds + BBASE + buf * 8192 + ch * 512);
    }
  };

  f32x4 acc[MIF][4];
#pragma unroll
  for (int i = 0; i < MIF; ++i)
#pragma unroll
    for (int j = 0; j < 4; ++j) acc[i][j] = f32x4{0.f, 0.f, 0.f, 0.f};

  // prologue: tiles 0,1 staged; drain tile 0, keep tile 1 in flight
  stageA(0, 0); stageB(0, 0); stageA(1, 1); stageB(1, 1);
  if constexpr (MIF == 8) { asm volatile("s_waitcnt vmcnt(4)" ::: "memory"); }
  else                    { asm volatile("s_waitcnt vmcnt(3)" ::: "memory"); }
  __builtin_amdgcn_s_barrier();

  for (int t = 0; t < NT; ++t) {
    const int cur = t % 3;
    const unsigned short* Ac = lds + cur * ABUF;
    const unsigned short* Bc = lds + BBASE + cur * 8192;
    const bool more = (t + 2 < NT);
    const int nbuf = (t + 2) % 3;
    // ---- phase 0: read A(first half) + B(all); stage A(t+2); MFMA
    bf16x8 af[MIF], bfr[4];
#pragma unroll
    for (int mi = 0; mi < MIF / 2; ++mi) {
      int arow = wm * (MIF * 16) + mi * 16 + c;
      af[mi] = *(const bf16x8*)((const char*)Ac + arow * 64 + ((g * 16) ^ swz));
    }
#pragma unroll
    for (int ni = 0; ni < 4; ++ni) {
      int brow = wn * 64 + ni * 16 + c;
      bfr[ni] = *(const bf16x8*)((const char*)Bc + brow * 64 + ((g * 16) ^ swz));
    }
    if (more) stageA(t + 2, nbuf);
    __builtin_amdgcn_s_barrier();
    asm volatile("s_waitcnt lgkmcnt(0)" ::: "memory");
    __builtin_amdgcn_sched_barrier(0);
    __builtin_amdgcn_s_setprio(1);
#pragma unroll
    for (int mi = 0; mi < MIF / 2; ++mi)
#pragma unroll
      for (int ni = 0; ni < 4; ++ni)
        acc[mi][ni] = MFMA16(af[mi], bfr[ni], acc[mi][ni]);
    __builtin_amdgcn_s_setprio(0);
    __builtin_amdgcn_s_barrier();
    // ---- phase 1: read A(second half); stage B(t+2); MFMA; counted drain
#pragma unroll
    for (int mi = MIF / 2; mi < MIF; ++mi) {
      int arow = wm * (MIF * 16) + mi * 16 + c;
      af[mi] = *(const bf16x8*)((const char*)Ac + arow * 64 + ((g * 16) ^ swz));
    }
    if (more) stageB(t + 2, nbuf);
    __builtin_amdgcn_s_barrier();
    asm volatile("s_waitcnt lgkmcnt(0)" ::: "memory");
    __builtin_amdgcn_sched_barrier(0);
    __builtin_amdgcn_s_setprio(1);
#pragma unroll
    for (int mi = MIF / 2; mi < MIF; ++mi)
#pragma unroll
      for (int ni = 0; ni < 4; ++ni)
        acc[mi][ni] = MFMA16(af[mi], bfr[ni], acc[mi][ni]);
    __builtin_amdgcn_s_setprio(0);
    if (more) {
      if constexpr (MIF == 8) { asm volatile("s_waitcnt vmcnt(4)" ::: "memory"); }
      else                    { asm volatile("s_waitcnt vmcnt(3)" ::: "memory"); }
    } else {
      asm volatile("s_waitcnt vmcnt(0)" ::: "memory");
    }
    __builtin_amdgcn_s_barrier();
  }

  // ---- epilogue
#pragma unroll
  for (int mi = 0; mi < MIF; ++mi)
#pragma unroll
    for (int ni = 0; ni < 4; ++ni)
#pragma unroll
      for (int r4 = 0; r4 < 4; ++r4) {
        float v = acc[mi][ni][r4];
        int mg = m0 + wm * (MIF * 16) + mi * 16 + g * 4 + r4;
        int ng = n0 + wn * 64 + ni * 16 + c;
        if (EPI == 0) {
          int which = ng >> 10, rem = ng & 1023;
          int hh = rem >> 6, dd = rem & 63;
          int bb = mg >> 11, tt = mg & 2047;
          size_t idx = (size_t)which * 8388608u + ((size_t)(bb * 16 + hh) * 2048 + tt) * 64 + dd;
          obf[idx] = f2bf(v);
        } else {
          of32[(size_t)mg * N + ng] = v;
        }
      }
}

// ---------------------------------------------------------------- flash attention (causal, swapped-QK^T)
__global__ __launch_bounds__(256, 6)
void attn_fwd(const unsigned short* __restrict__ qb,
              const unsigned short* __restrict__ kb,
              const unsigned short* __restrict__ vb,
              unsigned short* __restrict__ yb) {
  __shared__ unsigned short Kt[64 * 64];
  __shared__ unsigned short Vt[64 * 64];
  __shared__ unsigned short Pl[4 * 16 * 72];
  const int tid = threadIdx.x, w = tid >> 6, lane = tid & 63;
  const int c = lane & 15, g = lane >> 4;
  const int bh = blockIdx.x & 63;
  const int qt = 31 - (blockIdx.x >> 6);
  const int q0 = qt * 64;
  const int b = bh >> 4, h = bh & 15;
  const size_t hb = (size_t)bh * 131072;
  const float GAM = 0.125f * 1.44269504089f;

  const unsigned short* qp = qb + hb + (size_t)(q0 + w * 16 + c) * 64;
  bf16x8 qf0 = *(const bf16x8*)(qp + g * 8);
  bf16x8 qf1 = *(const bf16x8*)(qp + 32 + g * 8);

  f32x4 yacc[4];
#pragma unroll
  for (int i = 0; i < 4; ++i) yacc[i] = f32x4{0.f, 0.f, 0.f, 0.f};
  float mrun = -1e30f, lsum = 0.f;
  unsigned short* pw = Pl + w * (16 * 72);

  for (int kv = 0; kv <= qt; ++kv) {
    const int kv0 = kv * 64;
    const bool diag = (kv == qt);
    if (kv) __syncthreads();
#pragma unroll
    for (int r = 0; r < 2; ++r) {
      int chunk = w * 2 + r;
      int row = chunk * 8 + (lane >> 3);
      int bo = (lane & 7) * 16;
      int sbo = bo ^ ((row & 7) << 4);
      gll16((const char*)(kb + hb + (size_t)(kv0 + row) * 64) + sbo, Kt + chunk * 512);
    }
    {
      int kv2 = (lane & 31) * 2;
      int dblk = w * 16 + (lane >> 5) * 8;
      const unsigned short* vp = vb + hb + (size_t)(kv0 + kv2) * 64 + dblk;
      bf16x8 r0 = *(const bf16x8*)(vp);
      bf16x8 r1 = *(const bf16x8*)(vp + 64);
#pragma unroll
      for (int i = 0; i < 8; ++i) {
        int d = dblk + i;
        unsigned pk2 = ((unsigned)(unsigned short)r0[i]) | (((unsigned)(unsigned short)r1[i]) << 16);
        *(unsigned*)(Vt + d * 64 + (kv2 ^ ((d & 7) << 3))) = pk2;
      }
    }
    __syncthreads();

    f32x4 sacc[4];
#pragma unroll
    for (int nt = 0; nt < 4; ++nt) sacc[nt] = f32x4{0.f, 0.f, 0.f, 0.f};
#pragma unroll
    for (int kk = 0; kk < 2; ++kk)
#pragma unroll
      for (int nt = 0; nt < 4; ++nt) {
        int row = nt * 16 + c;
        bf16x8 kf = *(const bf16x8*)(Kt + row * 64 + ((kk * 32 + g * 8) ^ ((row & 7) << 3)));
        sacc[nt] = MFMA16(kf, (kk ? qf1 : qf0), sacc[nt]);
      }

    if (diag) {
      int ql = w * 16 + c;
#pragma unroll
      for (int nt = 0; nt < 4; ++nt)
#pragma unroll
        for (int r = 0; r < 4; ++r)
          if (nt * 16 + g * 4 + r > ql) sacc[nt][r] = -1e30f;
    }

    float m0 = -1e30f;
#pragma unroll
    for (int nt = 0; nt < 4; ++nt) {
      float a = fmaxf(fmaxf(sacc[nt][0], sacc[nt][1]), fmaxf(sacc[nt][2], sacc[nt][3]));
      m0 = fmaxf(m0, a);
    }
    m0 = fmaxf(m0, __shfl_xor(m0, 16));
    m0 = fmaxf(m0, __shfl_xor(m0, 32));

    if (__any(m0 > mrun + 32.0f)) {
      float mnew = fmaxf(mrun, m0);
      float corr = __builtin_amdgcn_exp2f(GAM * (mrun - mnew));
      lsum *= corr;
#pragma unroll
      for (int dt = 0; dt < 4; ++dt) yacc[dt] *= corr;
      mrun = mnew;
    }

    float bexp = -GAM * mrun;
    float psum = 0.f;
#pragma unroll
    for (int nt = 0; nt < 4; ++nt) {
      float p0 = __builtin_amdgcn_exp2f(fmaf(sacc[nt][0], GAM, bexp));
      float p1 = __builtin_amdgcn_exp2f(fmaf(sacc[nt][1], GAM, bexp));
      float p2 = __builtin_amdgcn_exp2f(fmaf(sacc[nt][2], GAM, bexp));
      float p3 = __builtin_amdgcn_exp2f(fmaf(sacc[nt][3], GAM, bexp));
      psum += (p0 + p1) + (p2 + p3);
      uint2v pkv;
      pkv[0] = pack_bf2(p0, p1);
      pkv[1] = pack_bf2(p2, p3);
      *(uint2v*)(pw + c * 72 + nt * 16 + g * 4) = pkv;
    }
    lsum += psum;

#pragma unroll
    for (int kk = 0; kk < 2; ++kk) {
      bf16x8 pb = *(const bf16x8*)(pw + c * 72 + kk * 32 + g * 8);
#pragma unroll
      for (int dt = 0; dt < 4; ++dt) {
        int n = dt * 16 + c;
        bf16x8 vf = *(const bf16x8*)(Vt + n * 64 + ((kk * 32 + g * 8) ^ ((n & 7) << 3)));
        yacc[dt] = MFMA16(vf, pb, yacc[dt]);
      }
    }
  }

  lsum += __shfl_xor(lsum, 16);
  lsum += __shfl_xor(lsum, 32);
  float inv = 1.0f / lsum;
  int row = q0 + w * 16 + c;
  unsigned short* yp = yb + ((size_t)(b * 2048 + row)) * 1024 + h * 64;
#pragma unroll
  for (int dt = 0; dt < 4; ++dt) {
    uint2v pkv;
    pkv[0] = pack_bf2(yacc[dt][0] * inv, yacc[dt][1] * inv);
    pkv[1] = pack_bf2(yacc[dt][2] * inv, yacc[dt][3] * inv);
    *(uint2v*)(yp + dt * 16 + g * 4) = pkv;
  }
}

// ---------------------------------------------------------------- launch
extern "C" void kernel_launch(void* const* d_in, const int* in_sizes, int n_in,
                              void* d_out, int out_size, void* d_ws, size_t ws_size,
                              hipStream_t stream) {
  const float* x     = (const float*)d_in[0];
  const float* wqkv  = (const float*)d_in[1];
  const float* wproj = (const float*)d_in[2];
  float* out = (float*)d_out;

  unsigned short* ws     = (unsigned short*)d_ws;
  unsigned short* xb     = ws;                       // 8388608
  unsigned short* wqkvb  = xb + 8388608;             // 3145728
  unsigned short* wprojb = wqkvb + 3145728;          // 1048576
  unsigned short* qkvb   = wprojb + 1048576;         // 3 * 8388608 (q,k,v)
  unsigned short* yb     = qkvb + 3 * 8388608;       // 8388608

  cvt_f32_bf16<<<8192, 256, 0, stream>>>(x, xb, 8388608);
  cvt_f32_bf16<<<3072, 256, 0, stream>>>(wqkv, wqkvb, 3145728);
  cvt_f32_bf16<<<1024, 256, 0, stream>>>(wproj, wprojb, 1048576);

  // gemm1: BM=256 BN=256 BK=32, 3-ring A+B: LDS = 96 KiB. grid 32*12=384 (%8==0)
  gemm4p<0, 8><<<384, 512, 98304, stream>>>(xb, wqkvb, qkvb, nullptr, 8192, 3072, 1024);
  attn_fwd<<<2048, 256, 0, stream>>>(qkvb, qkvb + 8388608, qkvb + 2 * 8388608, yb);
  // gemm2: BM=128 BN=256: LDS = 72 KiB. grid 64*4=256 (%8==0)
  gemm4p<1, 4><<<256, 512, 73728, stream>>>(yb, wprojb, nullptr, out, 8192, 1024, 1024);
}

// Round 7
// 176.008 us; speedup vs baseline: 1.0526x; 1.0526x over previous
//
#include <hip/hip_runtime.h>
#include <hip/hip_bf16.h>

typedef __attribute__((ext_vector_type(8))) short bf16x8;
typedef __attribute__((ext_vector_type(4))) float f32x4;
typedef __attribute__((ext_vector_type(4))) unsigned short ushort4v;
typedef __attribute__((ext_vector_type(2))) unsigned uint2v;

__device__ __forceinline__ unsigned short f2bf(float f) {
  union { float f; unsigned u; } v; v.f = f;
  unsigned r = v.u + 0x7FFFu + ((v.u >> 16) & 1u);
  return (unsigned short)(r >> 16);
}

__device__ __forceinline__ unsigned pack_bf2(float lo, float hi) {
  __hip_bfloat162 h = __float22bfloat162_rn(make_float2(lo, hi));
  union { __hip_bfloat162 h; unsigned u; } cv; cv.h = h; return cv.u;
}

__device__ __forceinline__ void gll16(const void* g, void* l) {
  __builtin_amdgcn_global_load_lds((const __attribute__((address_space(1))) void*)g,
                                   (__attribute__((address_space(3))) void*)l, 16, 0, 0);
}

#define MFMA16(a, b, c) __builtin_amdgcn_mfma_f32_16x16x32_bf16((a), (b), (c), 0, 0, 0)

// ---------------------------------------------------------------- convert
__global__ void cvt_f32_bf16(const float* __restrict__ s, unsigned short* __restrict__ d, int n) {
  int i = (blockIdx.x * blockDim.x + threadIdx.x) * 4;
  if (i >= n) return;
  float4 f = *(const float4*)(s + i);
  ushort4v r;
  r[0] = f2bf(f.x); r[1] = f2bf(f.y); r[2] = f2bf(f.z); r[3] = f2bf(f.w);
  *(ushort4v*)(d + i) = r;
}

// ---------------------------------------------------------------- GEMM NT, m201-style 8-phase
// BM=BN=256, BK=64. 512 thr, 8 waves (2M x 4N), per-wave 128x64.
// LDS (bytes): A(par,half) = par*32768 + half*16384 ; B = 65536 + same. Total 128 KiB.
// Iter covers K-tiles u (par0), u+1 (par1) in 8 phases; 1 half-tile staged per phase;
// vmcnt(4) only at phases 4 and 8 (ledger: each drain lands exactly the next 4 phases' reads).
template<int EPI>
__global__ __launch_bounds__(512, 1)
void gemm8p(const unsigned short* __restrict__ A,
            const unsigned short* __restrict__ B,
            unsigned short* __restrict__ obf,
            float* __restrict__ of32,
            int M, int N, int K) {
  extern __shared__ char lds[];
  const int tid = threadIdx.x, wid = tid >> 6, lane = tid & 63;
  const int c = lane & 15, g = lane >> 4;
  const int wm = wid >> 2, wn = wid & 3;
  const int nbn = N >> 8;
  const int nwg = gridDim.x;
  const int wg = (blockIdx.x & 7) * (nwg >> 3) + (blockIdx.x >> 3);  // XCD swizzle (nwg%8==0)
  const int m0 = (wg / nbn) * 256, n0 = (wg % nbn) * 256;
  const int NT = K >> 6, NT2 = NT >> 1;
  const size_t rb = (size_t)K * 2;     // global row bytes
  const int sw = (c & 7) << 4;         // ds_read XOR key over 8x16B slots (rows are 128B)

  // staging: thread covers row srow (of a 64-row chunk), pre-swizzled slot
  const int srow = tid >> 3;
  const int sslot = (tid & 7) ^ (srow & 7);
  const char* Ag = (const char*)A + (size_t)(m0 + srow) * rb + sslot * 16;
  const char* Bg = (const char*)B + (size_t)(n0 + srow) * rb + sslot * 16;
  char* ldsw = lds + wid * 1024;       // wave-uniform stage base (lane*16 added by HW)

  auto stg = [&](const char* G, int obase, int t, int h) {   // one half-tile: 2 x gll16
#pragma unroll
    for (int j = 0; j < 2; ++j)
      gll16(G + (size_t)(h * 128 + j * 64) * rb + t * 128,
            ldsw + obase + (t & 1) * 32768 + h * 16384 + j * 8192);
  };

  f32x4 acc[8][4];
#pragma unroll
  for (int i = 0; i < 8; ++i)
#pragma unroll
    for (int j = 0; j < 4; ++j) acc[i][j] = f32x4{0.f, 0.f, 0.f, 0.f};

  bf16x8 afA[4][2], afB[4][2], bl[2][2], bh[2][2];

  auto rdA = [&](int par, int s, bf16x8 af[4][2]) {
    const char* base = lds + par * 32768 + wm * 16384;
#pragma unroll
    for (int mi = 0; mi < 4; ++mi) {
      int lr = s * 64 + mi * 16 + c;
#pragma unroll
      for (int kk = 0; kk < 2; ++kk)
        af[mi][kk] = *(const bf16x8*)(base + lr * 128 + ((kk * 64 + g * 16) ^ sw));
    }
  };
  auto rdB = [&](int par, int s, bf16x8 bf[2][2]) {
    const char* base = lds + 65536 + par * 32768 + (wn >> 1) * 16384;
#pragma unroll
    for (int ni = 0; ni < 2; ++ni) {
      int lr = (wn & 1) * 64 + s * 32 + ni * 16 + c;
#pragma unroll
      for (int kk = 0; kk < 2; ++kk)
        bf[ni][kk] = *(const bf16x8*)(base + lr * 128 + ((kk * 64 + g * 16) ^ sw));
    }
  };
  auto mma = [&](bf16x8 af[4][2], bf16x8 bf[2][2], int sm, int sn) {
    asm volatile("s_waitcnt lgkmcnt(0)" ::: "memory");
    __builtin_amdgcn_sched_barrier(0);
    __builtin_amdgcn_s_setprio(1);
#pragma unroll
    for (int kk = 0; kk < 2; ++kk)
#pragma unroll
      for (int mi = 0; mi < 4; ++mi)
#pragma unroll
        for (int ni = 0; ni < 2; ++ni)
          acc[sm * 4 + mi][sn * 2 + ni] = MFMA16(af[mi][kk], bf[ni][kk], acc[sm * 4 + mi][sn * 2 + ni]);
    __builtin_amdgcn_s_setprio(0);
  };

  // 4 phases covering K-tile `par`; stages: A(tA,h0/h1) at P1/P2, B(tB,h0/h1) at P3/P4
  auto halfIter = [&](int par, int tA, bool vA, int tB, bool vB, bool drainAll) {
    // P1
    rdA(par, 0, afA); rdB(par, 0, bl);
    if (vA) stg(Ag, 0, tA, 0);
    __builtin_amdgcn_s_barrier();
    mma(afA, bl, 0, 0);
    __builtin_amdgcn_s_barrier();
    // P2
    rdB(par, 1, bh);
    if (vA) stg(Ag, 0, tA, 1);
    __builtin_amdgcn_s_barrier();
    mma(afA, bh, 0, 1);
    __builtin_amdgcn_s_barrier();
    // P3
    rdA(par, 1, afB);
    if (vB) stg(Bg, 65536, tB, 0);
    __builtin_amdgcn_s_barrier();
    mma(afB, bh, 1, 1);
    __builtin_amdgcn_s_barrier();
    // P4
    if (vB) stg(Bg, 65536, tB, 1);
    __builtin_amdgcn_s_barrier();
    mma(afB, bl, 1, 0);
    if (drainAll) { asm volatile("s_waitcnt vmcnt(0)" ::: "memory"); }
    else          { asm volatile("s_waitcnt vmcnt(4)" ::: "memory"); }
    __builtin_amdgcn_s_barrier();
  };

  // prologue: B0(h0,h1), A0(h0,h1), B1(h0,h1); drain so A0,B0 landed (keep B1's 4 in flight)
  stg(Bg, 65536, 0, 0); stg(Bg, 65536, 0, 1);
  stg(Ag, 0, 0, 0);     stg(Ag, 0, 0, 1);
  stg(Bg, 65536, 1, 0); stg(Bg, 65536, 1, 1);
  asm volatile("s_waitcnt vmcnt(4)" ::: "memory");
  __builtin_amdgcn_s_barrier();

  for (int i = 0; i < NT2; ++i) {
    const int u = 2 * i;
    const bool last = (i == NT2 - 1);
    // tiles u (par0) and u+1 (par1); stage A(u+1) [always], B(u+2), A(u+2), B(u+3) [if exist]
    halfIter(0, u + 1, true,  u + 2, !last, last);
    halfIter(1, u + 2, !last, u + 3, !last, last);
  }

  // ---- epilogue
#pragma unroll
  for (int mi = 0; mi < 8; ++mi)
#pragma unroll
    for (int ni = 0; ni < 4; ++ni)
#pragma unroll
      for (int r4 = 0; r4 < 4; ++r4) {
        float v = acc[mi][ni][r4];
        int mg = m0 + wm * 128 + mi * 16 + g * 4 + r4;
        int ng = n0 + wn * 64 + ni * 16 + c;
        if (EPI == 0) {
          int which = ng >> 10, rem = ng & 1023;
          int hh = rem >> 6, dd = rem & 63;
          int bb = mg >> 11, tt = mg & 2047;
          size_t idx = (size_t)which * 8388608u + ((size_t)(bb * 16 + hh) * 2048 + tt) * 64 + dd;
          obf[idx] = f2bf(v);
        } else {
          of32[(size_t)mg * N + ng] = v;
        }
      }
}

// ---------------------------------------------------------------- flash attention (causal, swapped-QK^T)
__global__ __launch_bounds__(256, 6)
void attn_fwd(const unsigned short* __restrict__ qb,
              const unsigned short* __restrict__ kb,
              const unsigned short* __restrict__ vb,
              unsigned short* __restrict__ yb) {
  __shared__ unsigned short Kt[64 * 64];
  __shared__ unsigned short Vt[64 * 64];
  __shared__ unsigned short Pl[4 * 16 * 72];
  const int tid = threadIdx.x, w = tid >> 6, lane = tid & 63;
  const int c = lane & 15, g = lane >> 4;
  const int bh = blockIdx.x & 63;
  const int qt = 31 - (blockIdx.x >> 6);
  const int q0 = qt * 64;
  const int b = bh >> 4, h = bh & 15;
  const size_t hb = (size_t)bh * 131072;
  const float GAM = 0.125f * 1.44269504089f;

  const unsigned short* qp = qb + hb + (size_t)(q0 + w * 16 + c) * 64;
  bf16x8 qf0 = *(const bf16x8*)(qp + g * 8);
  bf16x8 qf1 = *(const bf16x8*)(qp + 32 + g * 8);

  f32x4 yacc[4];
#pragma unroll
  for (int i = 0; i < 4; ++i) yacc[i] = f32x4{0.f, 0.f, 0.f, 0.f};
  float mrun = -1e30f, lsum = 0.f;
  unsigned short* pw = Pl + w * (16 * 72);

  for (int kv = 0; kv <= qt; ++kv) {
    const int kv0 = kv * 64;
    const bool diag = (kv == qt);
    if (kv) __syncthreads();
#pragma unroll
    for (int r = 0; r < 2; ++r) {
      int chunk = w * 2 + r;
      int row = chunk * 8 + (lane >> 3);
      int bo = (lane & 7) * 16;
      int sbo = bo ^ ((row & 7) << 4);
      gll16((const char*)(kb + hb + (size_t)(kv0 + row) * 64) + sbo, Kt + chunk * 512);
    }
    {
      int kv2 = (lane & 31) * 2;
      int dblk = w * 16 + (lane >> 5) * 8;
      const unsigned short* vp = vb + hb + (size_t)(kv0 + kv2) * 64 + dblk;
      bf16x8 r0 = *(const bf16x8*)(vp);
      bf16x8 r1 = *(const bf16x8*)(vp + 64);
#pragma unroll
      for (int i = 0; i < 8; ++i) {
        int d = dblk + i;
        unsigned pk2 = ((unsigned)(unsigned short)r0[i]) | (((unsigned)(unsigned short)r1[i]) << 16);
        *(unsigned*)(Vt + d * 64 + (kv2 ^ ((d & 7) << 3))) = pk2;
      }
    }
    __syncthreads();

    f32x4 sacc[4];
#pragma unroll
    for (int nt = 0; nt < 4; ++nt) sacc[nt] = f32x4{0.f, 0.f, 0.f, 0.f};
#pragma unroll
    for (int kk = 0; kk < 2; ++kk)
#pragma unroll
      for (int nt = 0; nt < 4; ++nt) {
        int row = nt * 16 + c;
        bf16x8 kf = *(const bf16x8*)(Kt + row * 64 + ((kk * 32 + g * 8) ^ ((row & 7) << 3)));
        sacc[nt] = MFMA16(kf, (kk ? qf1 : qf0), sacc[nt]);
      }

    if (diag) {
      int ql = w * 16 + c;
#pragma unroll
      for (int nt = 0; nt < 4; ++nt)
#pragma unroll
        for (int r = 0; r < 4; ++r)
          if (nt * 16 + g * 4 + r > ql) sacc[nt][r] = -1e30f;
    }

    float m0 = -1e30f;
#pragma unroll
    for (int nt = 0; nt < 4; ++nt) {
      float a = fmaxf(fmaxf(sacc[nt][0], sacc[nt][1]), fmaxf(sacc[nt][2], sacc[nt][3]));
      m0 = fmaxf(m0, a);
    }
    m0 = fmaxf(m0, __shfl_xor(m0, 16));
    m0 = fmaxf(m0, __shfl_xor(m0, 32));

    if (__any(m0 > mrun + 32.0f)) {
      float mnew = fmaxf(mrun, m0);
      float corr = __builtin_amdgcn_exp2f(GAM * (mrun - mnew));
      lsum *= corr;
#pragma unroll
      for (int dt = 0; dt < 4; ++dt) yacc[dt] *= corr;
      mrun = mnew;
    }

    float bexp = -GAM * mrun;
    float psum = 0.f;
#pragma unroll
    for (int nt = 0; nt < 4; ++nt) {
      float p0 = __builtin_amdgcn_exp2f(fmaf(sacc[nt][0], GAM, bexp));
      float p1 = __builtin_amdgcn_exp2f(fmaf(sacc[nt][1], GAM, bexp));
      float p2 = __builtin_amdgcn_exp2f(fmaf(sacc[nt][2], GAM, bexp));
      float p3 = __builtin_amdgcn_exp2f(fmaf(sacc[nt][3], GAM, bexp));
      psum += (p0 + p1) + (p2 + p3);
      uint2v pkv;
      pkv[0] = pack_bf2(p0, p1);
      pkv[1] = pack_bf2(p2, p3);
      *(uint2v*)(pw + c * 72 + nt * 16 + g * 4) = pkv;
    }
    lsum += psum;

#pragma unroll
    for (int kk = 0; kk < 2; ++kk) {
      bf16x8 pb = *(const bf16x8*)(pw + c * 72 + kk * 32 + g * 8);
#pragma unroll
      for (int dt = 0; dt < 4; ++dt) {
        int n = dt * 16 + c;
        bf16x8 vf = *(const bf16x8*)(Vt + n * 64 + ((kk * 32 + g * 8) ^ ((n & 7) << 3)));
        yacc[dt] = MFMA16(vf, pb, yacc[dt]);
      }
    }
  }

  lsum += __shfl_xor(lsum, 16);
  lsum += __shfl_xor(lsum, 32);
  float inv = 1.0f / lsum;
  int row = q0 + w * 16 + c;
  unsigned short* yp = yb + ((size_t)(b * 2048 + row)) * 1024 + h * 64;
#pragma unroll
  for (int dt = 0; dt < 4; ++dt) {
    uint2v pkv;
    pkv[0] = pack_bf2(yacc[dt][0] * inv, yacc[dt][1] * inv);
    pkv[1] = pack_bf2(yacc[dt][2] * inv, yacc[dt][3] * inv);
    *(uint2v*)(yp + dt * 16 + g * 4) = pkv;
  }
}

// ---------------------------------------------------------------- launch
extern "C" void kernel_launch(void* const* d_in, const int* in_sizes, int n_in,
                              void* d_out, int out_size, void* d_ws, size_t ws_size,
                              hipStream_t stream) {
  const float* x     = (const float*)d_in[0];
  const float* wqkv  = (const float*)d_in[1];
  const float* wproj = (const float*)d_in[2];
  float* out = (float*)d_out;

  unsigned short* ws     = (unsigned short*)d_ws;
  unsigned short* xb     = ws;                       // 8388608
  unsigned short* wqkvb  = xb + 8388608;             // 3145728
  unsigned short* wprojb = wqkvb + 3145728;          // 1048576
  unsigned short* qkvb   = wprojb + 1048576;         // 3 * 8388608 (q,k,v)
  unsigned short* yb     = qkvb + 3 * 8388608;       // 8388608

  cvt_f32_bf16<<<8192, 256, 0, stream>>>(x, xb, 8388608);
  cvt_f32_bf16<<<3072, 256, 0, stream>>>(wqkv, wqkvb, 3145728);
  cvt_f32_bf16<<<1024, 256, 0, stream>>>(wproj, wprojb, 1048576);

  // 128 KiB dynamic LDS; grids are %8==0 for the XCD swizzle
  gemm8p<0><<<384, 512, 131072, stream>>>(xb, wqkvb, qkvb, nullptr, 8192, 3072, 1024);
  attn_fwd<<<2048, 256, 0, stream>>>(qkvb, qkvb + 8388608, qkvb + 2 * 8388608, yb);
  gemm8p<1><<<128, 512, 131072, stream>>>(yb, wprojb, nullptr, out, 8192, 1024, 1024);
}